// Round 4
// baseline (706.888 us; speedup 1.0000x reference)
//
#include <hip/hip_runtime.h>
#include <hip/hip_bf16.h>

typedef __bf16 bf16;
typedef __bf16 bf16x4 __attribute__((ext_vector_type(4)));
typedef __bf16 bf16x8 __attribute__((ext_vector_type(8)));
typedef float f32x4 __attribute__((ext_vector_type(4)));

// problem sizes
#define NN 8192
#define DIN 128
#define DTH 256
#define DH 64

// workspace layout (bytes)
#define OFF_BN   0                               // 256 f32 bn sums (1 KB)
#define OFF_PACC 1024                            // 2 (js) * 8192*64 f32
#define OFF_PDEN (OFF_PACC + 2*8192*64*4)        // 2 (js) * 8192 f32
#define OFF_HX   (OFF_PDEN + 2*8192*4)           // 8192*256 bf16 Hx
#define OFF_X2T  (OFF_HX + 8192*256*2)           // 64*8192 bf16 X2 transposed
#define ZERO_BYTES 1024                          // only bn sums need zeroing

#define E_CONST 2.71828182845904523f

// ---------------------------------------------------------------------------
__global__ __launch_bounds__(256) void k_bn_stats(const float* __restrict__ H,
                                                  float* __restrict__ bns) {
    __shared__ float s1[256], s2[256];
    int t = threadIdx.x;
    int f = t & 127, rh = t >> 7;
    int r0 = blockIdx.x * 32 + rh * 16;
    float a = 0.f, b = 0.f;
#pragma unroll
    for (int rr = 0; rr < 16; ++rr) {
        float x = H[(size_t)(r0 + rr) * DIN + f];
        a += x; b += x * x;
    }
    s1[t] = a; s2[t] = b;
    __syncthreads();
    if (t < 128) {
        atomicAdd(&bns[f], s1[t] + s1[t + 128]);
        atomicAdd(&bns[128 + f], s2[t] + s2[t + 128]);
    }
}

// ---------------------------------------------------------------------------
__global__ __launch_bounds__(256) void k_project(
    const float* __restrict__ H, const float* __restrict__ bns,
    const float* __restrict__ gamma, const float* __restrict__ beta,
    const float* __restrict__ Wt, const float* __restrict__ bt,
    const float* __restrict__ W1, const float* __restrict__ b1,
    const float* __restrict__ W2, const float* __restrict__ b2,
    bf16* __restrict__ Hx, bf16* __restrict__ X2T, float* __restrict__ out)
{
    __shared__ float Hn[16 * 128];
    int t = threadIdx.x;
    int r0 = blockIdx.x * 16;
    {
        int f = t & 127;
        float mean = bns[f] * (1.f / 8192.f);
        float var  = bns[128 + f] * (1.f / 8192.f) - mean * mean;
        float sc = rsqrtf(var + 1e-5f) * gamma[f];
        float sh = beta[f];
        int rb = t >> 7;
#pragma unroll
        for (int p = 0; p < 8; ++p) {
            int row = rb + p * 2;
            float x = H[(size_t)(r0 + row) * DIN + f];
            Hn[row * 128 + f] = (x - mean) * sc + sh;
        }
    }
    __syncthreads();
    {
        int c0 = t & 63, rg = t >> 6;
        float acc[4][4];
#pragma unroll
        for (int i = 0; i < 4; ++i)
#pragma unroll
            for (int j = 0; j < 4; ++j) acc[i][j] = 0.f;
        for (int k = 0; k < 128; ++k) {
            float h[4];
#pragma unroll
            for (int rr = 0; rr < 4; ++rr) h[rr] = Hn[(rg * 4 + rr) * 128 + k];
#pragma unroll
            for (int cc = 0; cc < 4; ++cc) {
                float wv = Wt[k * DTH + c0 + 64 * cc];
#pragma unroll
                for (int rr = 0; rr < 4; ++rr) acc[rr][cc] += h[rr] * wv;
            }
        }
#pragma unroll
        for (int rr = 0; rr < 4; ++rr) {
            int row = r0 + rg * 4 + rr;
#pragma unroll
            for (int cc = 0; cc < 4; ++cc) {
                int c = c0 + 64 * cc;
                Hx[(size_t)row * DTH + c] = (bf16)(acc[rr][cc] + bt[c]);
            }
        }
    }
    {
        int c = t & 63, rg = t >> 6;
        float a1[4] = {0,0,0,0}, a2[4] = {0,0,0,0};
        for (int k = 0; k < 128; ++k) {
            float w1 = W1[k * DH + c], w2 = W2[k * DH + c];
#pragma unroll
            for (int rr = 0; rr < 4; ++rr) {
                float h = Hn[(rg * 4 + rr) * 128 + k];
                a1[rr] += h * w1; a2[rr] += h * w2;
            }
        }
#pragma unroll
        for (int rr = 0; rr < 4; ++rr) {
            int row = r0 + rg * 4 + rr;
            float v1 = a1[rr] + b1[c];
            out[(size_t)row * 128 + c] = v1 > 0.f ? v1 : 0.01f * v1;
            X2T[(size_t)c * NN + row] = (bf16)(a2[rr] + b2[c]);
        }
    }
}

// ---------------------------------------------------------------------------
// Fused v5: per-wave LDS double-buffer + global_load_lds + counted vmcnt.
// No __syncthreads in the main loop (Hx_j rows are wave-private). Fixed VMEM
// issue order per pair-iteration (8 lds + 2 A + 8 lds + 2 A + 8 x2t = 28),
// pinned with sched_barrier(0); three vmcnt(20) waits give: aj buffers ready
// exactly when read, A-mask 2 pairs deep (~1600cy > HBM 900cy), x2t 1 pair
// deep (~700cy > L2 250cy). LDS: 4 waves x 2 bufs x 8KB = 64KB -> 2 blk/CU.
// ds_read_b128 conflict-free via XOR chunk swizzle pre-applied on the
// global source address (gload_lds writes linearly: base + lane*16).
__device__ __forceinline__ void gl_lds16(const bf16* g, bf16* l) {
    __builtin_amdgcn_global_load_lds(
        (const __attribute__((address_space(1))) void*)g,
        (__attribute__((address_space(3))) void*)l, 16, 0, 0);
}

__global__ __launch_bounds__(256, 2) void k_fused(
    const float* __restrict__ A, const bf16* __restrict__ Hx,
    const bf16* __restrict__ X2T, float* __restrict__ pacc,
    float* __restrict__ pden)
{
    __shared__ __align__(16) bf16 AJ[4][2][4096];   // [wave][buf][16 rows x 256]

    int t = threadIdx.x;
    int w = t >> 6, l = t & 63;
    int q = l >> 4, li = l & 15;
    int bid = blockIdx.x;
    int rid = (bid & 7) * 64 + (bid >> 3);   // XCD swizzle, bijective (512%8==0)
    int ib = rid >> 1, js = rid & 1;
    int i0 = ib * 32;
    int jb = js * 4096;

    union U8 { uint2 u[2]; bf16x8 v; };

    bf16* B0 = &AJ[w][0][0];
    bf16* B1 = &AJ[w][1][0];

    // Hx_i B-fragments, register-resident all kernel
    bf16x8 hbI[2];
    f32x4 acc[4][2] = {{{0,0,0,0},{0,0,0,0}},{{0,0,0,0},{0,0,0,0}},
                       {{0,0,0,0},{0,0,0,0}},{{0,0,0,0},{0,0,0,0}}};
    float dp0 = 0.f, dp1 = 0.f;
    bf16x8 hbI0[8], hbI1[8];
#pragma unroll
    for (int ks = 0; ks < 8; ++ks) {
        hbI0[ks] = *(const bf16x8*)&Hx[(size_t)(i0 + li) * DTH + ks * 32 + q * 8];
        hbI1[ks] = *(const bf16x8*)&Hx[(size_t)(i0 + 16 + li) * DTH + ks * 32 + q * 8];
    }

    const float* avp = A + (size_t)(i0 + li) * NN + jb + w * 16 + q * 4;
    const bf16*  xp  = X2T + (size_t)li * NN + jb + w * 16 + q * 4;

    // stage chunk CH (64 j-rows; this wave's 16) into LDS buffer LB.
    // lane ll writes LDS byte ll*16 of each 1KB issue; source pre-swizzled:
    // row r = p*2 + (ll>>5), logical chunk = (ll&31) ^ (r&7).
    int lhi = l >> 5, lco = l & 31;
#define STAGE(LB, CH) {                                                        \
        const bf16* gs = Hx + (((size_t)(jb + (CH) * 64 + w * 16)) << 8);      \
        _Pragma("unroll")                                                      \
        for (int p = 0; p < 8; ++p) {                                          \
            int r_ = p * 2 + lhi;                                              \
            gl_lds16(gs + ((size_t)r_ << 8) + ((lco ^ (r_ & 7)) << 3),         \
                     (LB) + p * 512);                                          \
        } }

    // QK mfma sweep from LDS buffer (swizzled read)
#define QKS(LB, S0, S1)                                                        \
        _Pragma("unroll")                                                      \
        for (int ks = 0; ks < 8; ++ks) {                                       \
            bf16x8 aj = *(const bf16x8*)((LB) + li * 256 +                     \
                                         (((ks * 4 + q) ^ (li & 7)) << 3));    \
            S0 = __builtin_amdgcn_mfma_f32_16x16x32_bf16(aj, hbI0[ks], S0, 0, 0, 0); \
            S1 = __builtin_amdgcn_mfma_f32_16x16x32_bf16(aj, hbI1[ks], S1, 0, 0, 0); \
        }

#define GATE(SV0, SV1, AV, CH, PD0, PD1) {                                     \
        int jr0 = jb + (CH) * 64 + w * 16;                                     \
        _Pragma("unroll")                                                      \
        for (int n = 0; n < 2; ++n) {                                          \
            f32x4 sv = n ? (SV1) : (SV0);                                      \
            f32x4 am = (AV)[n];                                                \
            int ig = i0 + n * 16 + li;                                         \
            _Pragma("unroll")                                                  \
            for (int r = 0; r < 4; ++r) {                                      \
                float s = sv[r];                                               \
                float sig = __builtin_amdgcn_rcpf(1.f + __expf(-s));           \
                float wv = (am[r] > 0.f) ? __expf(sig) : 0.f;                  \
                int jc = jr0 + q * 4 + r;                                      \
                if (ig == jc) wv = E_CONST;                                    \
                if (n == 0) { dp0 += wv; PD0[r] = (bf16)wv; }                  \
                else        { dp1 += wv; PD1[r] = (bf16)wv; }                  \
            }                                                                  \
        } }

#define WAITVM20  asm volatile("s_waitcnt vmcnt(20)" ::: "memory")
#define SBAR      __builtin_amdgcn_sched_barrier(0)

    f32x4 avE_A[2], avO_A[2], avE_B[2], avO_B[2];
    uint2 xeA[4], xoA[4], xeB[4], xoB[4];

    // ---- prologue (order defines vmcnt positions: 8,2,8,2,8 then 4 extra)
    STAGE(B0, 0) SBAR;
    avE_A[0] = *(const f32x4*)(avp);
    avE_A[1] = *(const f32x4*)(avp + (size_t)16 * NN); SBAR;
    STAGE(B1, 1) SBAR;
    avO_A[0] = *(const f32x4*)(avp + 64);
    avO_A[1] = *(const f32x4*)(avp + (size_t)16 * NN + 64); SBAR;
#pragma unroll
    for (int ct = 0; ct < 4; ++ct) {
        xeA[ct] = *(const uint2*)(xp + (size_t)ct * 16 * NN);
        xoA[ct] = *(const uint2*)(xp + (size_t)ct * 16 * NN + 64);
    }
    SBAR;
    avE_B[0] = *(const f32x4*)(avp + 128);
    avE_B[1] = *(const f32x4*)(avp + (size_t)16 * NN + 128);
    avO_B[0] = *(const f32x4*)(avp + 192);
    avO_B[1] = *(const f32x4*)(avp + (size_t)16 * NN + 192); SBAR;

#define PAIR(PR, XEC, XOC, XEN, XON, AVE, AVO) {                               \
        const int pr = (PR);                                                   \
        WAITVM20; SBAR;                                                        \
        bf16x4 pe0, pe1, po0, po1;                                             \
        f32x4 s0 = {0,0,0,0}, s1 = {0,0,0,0};                                  \
        QKS(B0, s0, s1) SBAR;                                                  \
        { int c1 = (2*pr+2 < 64) ? 2*pr+2 : 62; STAGE(B0, c1) } SBAR;          \
        GATE(s0, s1, AVE, 2*pr, pe0, pe1) SBAR;                                \
        { int pn = (pr+2 < 32) ? pr+2 : 31;                                    \
          AVE[0] = *(const f32x4*)(avp + pn * 128);                            \
          AVE[1] = *(const f32x4*)(avp + (size_t)16 * NN + pn * 128); } SBAR;  \
        WAITVM20; SBAR;                                                        \
        f32x4 u0 = {0,0,0,0}, u1 = {0,0,0,0};                                  \
        QKS(B1, u0, u1) SBAR;                                                  \
        { int c3 = (2*pr+3 < 64) ? 2*pr+3 : 63; STAGE(B1, c3) } SBAR;          \
        GATE(u0, u1, AVO, 2*pr+1, po0, po1) SBAR;                              \
        { int pn = (pr+2 < 32) ? pr+2 : 31;                                    \
          AVO[0] = *(const f32x4*)(avp + 64 + pn * 128);                       \
          AVO[1] = *(const f32x4*)(avp + (size_t)16 * NN + 64 + pn * 128); } SBAR; \
        WAITVM20; SBAR;                                                        \
        { int px = (pr+1 < 32) ? pr+1 : 31;                                    \
          _Pragma("unroll")                                                    \
          for (int ct = 0; ct < 4; ++ct) {                                     \
            XEN[ct] = *(const uint2*)(xp + (size_t)ct * 16 * NN + px * 128);   \
            XON[ct] = *(const uint2*)(xp + (size_t)ct * 16 * NN + px * 128 + 64); \
          } } SBAR;                                                            \
        _Pragma("unroll")                                                      \
        for (int n = 0; n < 2; ++n) {                                          \
            bf16x8 pf;                                                         \
            bf16x4 pe = n ? pe1 : pe0, po = n ? po1 : po0;                     \
            pf[0]=pe[0]; pf[1]=pe[1]; pf[2]=pe[2]; pf[3]=pe[3];                \
            pf[4]=po[0]; pf[5]=po[1]; pf[6]=po[2]; pf[7]=po[3];                \
            _Pragma("unroll")                                                  \
            for (int ct = 0; ct < 4; ++ct) {                                   \
                U8 xf; xf.u[0] = XEC[ct]; xf.u[1] = XOC[ct];                   \
                acc[ct][n] = __builtin_amdgcn_mfma_f32_16x16x32_bf16(xf.v, pf, acc[ct][n], 0, 0, 0); \
            }                                                                  \
        } SBAR; }

    for (int pp = 0; pp < 16; ++pp) {
        PAIR(2*pp,     xeA, xoA, xeB, xoB, avE_A, avO_A)
        PAIR(2*pp + 1, xeB, xoB, xeA, xoA, avE_B, avO_B)
    }
#undef PAIR
#undef STAGE
#undef QKS
#undef GATE

    // drain pending DMAs before reusing AJ as reduction scratch
    asm volatile("s_waitcnt vmcnt(0)" ::: "memory");
    __syncthreads();

    // ---- epilogue: cross-wave reduce PV partials via LDS, plain stores ----
    float* Lf = (float*)AJ;
    float* po = pacc + (size_t)js * NN * DH;
#pragma unroll
    for (int ct = 0; ct < 4; ++ct)
#pragma unroll
        for (int n = 0; n < 2; ++n)
#pragma unroll
            for (int r = 0; r < 4; ++r)
                Lf[w * 2048 + (ct * 16 + q * 4 + r) * 32 + n * 16 + li] = acc[ct][n][r];
    __syncthreads();
#pragma unroll
    for (int p = 0; p < 8; ++p) {
        int idx = t + p * 256;
        float v = Lf[idx] + Lf[2048 + idx] + Lf[4096 + idx] + Lf[6144 + idx];
        po[(size_t)(i0 + (idx & 31)) * DH + (idx >> 5)] = v;
    }
    float dq0 = dp0, dq1 = dp1;
    dq0 += __shfl_xor(dq0, 16, 64); dq0 += __shfl_xor(dq0, 32, 64);
    dq1 += __shfl_xor(dq1, 16, 64); dq1 += __shfl_xor(dq1, 32, 64);
    __syncthreads();
    if (l < 16) { Lf[w * 32 + li] = dq0; Lf[w * 32 + 16 + li] = dq1; }
    __syncthreads();
    if (t < 32) {
        float v = Lf[t] + Lf[32 + t] + Lf[64 + t] + Lf[96 + t];
        pden[(size_t)js * NN + i0 + t] = v;
    }
}

// ---------------------------------------------------------------------------
__global__ __launch_bounds__(256) void k_finalize(const float* __restrict__ pacc,
                                                  const float* __restrict__ pden,
                                                  float* __restrict__ out)
{
    int e = blockIdx.x * 256 + threadIdx.x;
    int i = e >> 6, c = e & 63;
    float v = (pacc[e] + pacc[NN * DH + e]) / (pden[i] + pden[NN + i]);
    out[(size_t)i * 128 + 64 + c] = v > 0.f ? v : 0.01f * v;
}

// ---------------------------------------------------------------------------
extern "C" void kernel_launch(void* const* d_in, const int* in_sizes, int n_in,
                              void* d_out, int out_size, void* d_ws, size_t ws_size,
                              hipStream_t stream)
{
    const float* H     = (const float*)d_in[0];
    const float* A     = (const float*)d_in[1];
    const float* gamma = (const float*)d_in[2];
    const float* beta  = (const float*)d_in[3];
    const float* Wt    = (const float*)d_in[4];
    const float* bt    = (const float*)d_in[5];
    const float* W1    = (const float*)d_in[6];
    const float* b1    = (const float*)d_in[7];
    const float* W2    = (const float*)d_in[8];
    const float* b2    = (const float*)d_in[9];
    float* out = (float*)d_out;

    char* ws = (char*)d_ws;
    float* bns  = (float*)(ws + OFF_BN);
    float* pacc = (float*)(ws + OFF_PACC);
    float* pden = (float*)(ws + OFF_PDEN);
    bf16*  Hx   = (bf16*)(ws + OFF_HX);
    bf16*  X2T  = (bf16*)(ws + OFF_X2T);

    hipMemsetAsync(ws + OFF_BN, 0, ZERO_BYTES, stream);
    k_bn_stats<<<256, 256, 0, stream>>>(H, bns);
    k_project<<<512, 256, 0, stream>>>(H, bns, gamma, beta, Wt, bt, W1, b1, W2, b2,
                                       Hx, X2T, out);
    k_fused<<<512, 256, 0, stream>>>(A, Hx, X2T, pacc, pden);
    k_finalize<<<2048, 256, 0, stream>>>(pacc, pden, out);
}

// Round 5
// 601.509 us; speedup vs baseline: 1.1752x; 1.1752x over previous
//
#include <hip/hip_runtime.h>
#include <hip/hip_bf16.h>

typedef __bf16 bf16;
typedef __bf16 bf16x8 __attribute__((ext_vector_type(8)));
typedef float f32x4 __attribute__((ext_vector_type(4)));

// problem sizes
#define NN 8192
#define DIN 128
#define DTH 256
#define DH 64

// workspace layout (bytes)
#define OFF_BN   0                               // 256 f32 bn sums (1 KB)
#define OFF_PACC 1024                            // 4 (js) * 8192*64 f32 = 8 MB
#define OFF_PDEN (OFF_PACC + 4*8192*64*4)        // 4 (js) * 8192 f32
#define OFF_HX   (OFF_PDEN + 4*8192*4)           // 8192*256 bf16 Hx
#define OFF_X2T  (OFF_HX + 8192*256*2)           // 64*8192 bf16 X2 transposed
#define ZERO_BYTES 1024                          // only bn sums need zeroing

#define E_CONST 2.71828182845904523f

// ---------------------------------------------------------------------------
__global__ __launch_bounds__(256) void k_bn_stats(const float* __restrict__ H,
                                                  float* __restrict__ bns) {
    __shared__ float s1[256], s2[256];
    int t = threadIdx.x;
    int f = t & 127, rh = t >> 7;
    int r0 = blockIdx.x * 32 + rh * 16;
    float a = 0.f, b = 0.f;
#pragma unroll
    for (int rr = 0; rr < 16; ++rr) {
        float x = H[(size_t)(r0 + rr) * DIN + f];
        a += x; b += x * x;
    }
    s1[t] = a; s2[t] = b;
    __syncthreads();
    if (t < 128) {
        atomicAdd(&bns[f], s1[t] + s1[t + 128]);
        atomicAdd(&bns[128 + f], s2[t] + s2[t + 128]);
    }
}

// ---------------------------------------------------------------------------
__global__ __launch_bounds__(256) void k_project(
    const float* __restrict__ H, const float* __restrict__ bns,
    const float* __restrict__ gamma, const float* __restrict__ beta,
    const float* __restrict__ Wt, const float* __restrict__ bt,
    const float* __restrict__ W1, const float* __restrict__ b1,
    const float* __restrict__ W2, const float* __restrict__ b2,
    bf16* __restrict__ Hx, bf16* __restrict__ X2T, float* __restrict__ out)
{
    __shared__ float Hn[16 * 128];
    int t = threadIdx.x;
    int r0 = blockIdx.x * 16;
    {
        int f = t & 127;
        float mean = bns[f] * (1.f / 8192.f);
        float var  = bns[128 + f] * (1.f / 8192.f) - mean * mean;
        float sc = rsqrtf(var + 1e-5f) * gamma[f];
        float sh = beta[f];
        int rb = t >> 7;
#pragma unroll
        for (int p = 0; p < 8; ++p) {
            int row = rb + p * 2;
            float x = H[(size_t)(r0 + row) * DIN + f];
            Hn[row * 128 + f] = (x - mean) * sc + sh;
        }
    }
    __syncthreads();
    {
        int c0 = t & 63, rg = t >> 6;
        float acc[4][4];
#pragma unroll
        for (int i = 0; i < 4; ++i)
#pragma unroll
            for (int j = 0; j < 4; ++j) acc[i][j] = 0.f;
        for (int k = 0; k < 128; ++k) {
            float h[4];
#pragma unroll
            for (int rr = 0; rr < 4; ++rr) h[rr] = Hn[(rg * 4 + rr) * 128 + k];
#pragma unroll
            for (int cc = 0; cc < 4; ++cc) {
                float wv = Wt[k * DTH + c0 + 64 * cc];
#pragma unroll
                for (int rr = 0; rr < 4; ++rr) acc[rr][cc] += h[rr] * wv;
            }
        }
#pragma unroll
        for (int rr = 0; rr < 4; ++rr) {
            int row = r0 + rg * 4 + rr;
#pragma unroll
            for (int cc = 0; cc < 4; ++cc) {
                int c = c0 + 64 * cc;
                Hx[(size_t)row * DTH + c] = (bf16)(acc[rr][cc] + bt[c]);
            }
        }
    }
    {
        int c = t & 63, rg = t >> 6;
        float a1[4] = {0,0,0,0}, a2[4] = {0,0,0,0};
        for (int k = 0; k < 128; ++k) {
            float w1 = W1[k * DH + c], w2 = W2[k * DH + c];
#pragma unroll
            for (int rr = 0; rr < 4; ++rr) {
                float h = Hn[(rg * 4 + rr) * 128 + k];
                a1[rr] += h * w1; a2[rr] += h * w2;
            }
        }
#pragma unroll
        for (int rr = 0; rr < 4; ++rr) {
            int row = r0 + rg * 4 + rr;
            float v1 = a1[rr] + b1[c];
            out[(size_t)row * 128 + c] = v1 > 0.f ? v1 : 0.01f * v1;
            X2T[(size_t)c * NN + row] = (bf16)(a2[rr] + b2[c]);
        }
    }
}

// ---------------------------------------------------------------------------
// Fused v6: v1's proven dataflow at 2x occupancy.
//  - Latency-bound diagnosis: occupancy was pinned at 2 blocks/CU in ALL
//    prior rounds. Fix: LDS 70KB -> 36.5KB (hxj single-buffer [64][256]
//    XOR-swizzled + P only; afrag & PV-B fragments direct from L2-resident
//    global), grid 512 -> 1024 (js=4), __launch_bounds__(256,4).
//  - Staging via global_load_lds (zero staging VGPRs); register budget
//    ~120 < 128 cap (afrag 64, agg 8, dpart 8, av 8, xb 16, addr).
//  - 2 barriers/chunk; stage(ch+1)+A(ch+1) issued before PV for overlap.
#define LDP 72    // P row stride (64 + 8 pad)

__device__ __forceinline__ void gl_lds16(const bf16* g, bf16* l) {
    __builtin_amdgcn_global_load_lds(
        (const __attribute__((address_space(1))) void*)g,
        (__attribute__((address_space(3))) void*)l, 16, 0, 0);
}

__global__ __launch_bounds__(256, 4) void k_fused(
    const float* __restrict__ A, const bf16* __restrict__ Hx,
    const bf16* __restrict__ X2T, float* __restrict__ pacc,
    float* __restrict__ pden)
{
    __shared__ __align__(16) bf16 hxj[64 * 256];   // 32 KB, XOR chunk-swizzle
    __shared__ __align__(16) bf16 P[32 * LDP];     // 4.5 KB

    int t = threadIdx.x;
    int w = t >> 6, l = t & 63;
    int q = l >> 4, li = l & 15;
    int bid = blockIdx.x;
    int rid = (bid & 7) * 128 + (bid >> 3);   // XCD swizzle, bijective (1024%8==0)
    int ib = rid >> 2, js = rid & 3;
    int i0 = ib * 32;
    int jb = js * 2048;                        // 32 chunks of 64 j each

    // Hx_i A-fragments direct from global (Hx = 4MB, L2-resident)
    bf16x8 afrag[2][8];
#pragma unroll
    for (int mb = 0; mb < 2; ++mb)
#pragma unroll
        for (int ks = 0; ks < 8; ++ks)
            afrag[mb][ks] = *(const bf16x8*)&Hx[(size_t)(i0 + mb * 16 + li) * DTH + ks * 32 + q * 8];

    // staging: wave w owns hxj rows w*16..+15; 8 issues x (2 rows/issue).
    // LDS linear (wave-uniform base + lane*16); source pre-swizzled so that
    // lds[row][c] = global[row][c ^ (row&7)] (16B chunks).
    int lhi = l >> 5, lco = l & 31;
    bf16* ldw = hxj + w * 16 * 256;
#define STAGE(CH) {                                                            \
        const bf16* gs = Hx + ((size_t)(jb + (CH) * 64 + w * 16) << 8);        \
        _Pragma("unroll")                                                      \
        for (int p = 0; p < 8; ++p) {                                          \
            int r_ = p * 2 + lhi;                                              \
            gl_lds16(gs + ((size_t)r_ << 8) + ((lco ^ (r_ & 7)) << 3),         \
                     ldw + p * 512);                                           \
        } }

    // A gate values: 8 scalar dwords (64B-coalesced over the 16 li lanes)
    const float* ap = A + (size_t)(i0 + q * 4) * NN + jb + w * 16 + li;
    float av[8];
#define LOAD_AV(CH)                                                            \
        _Pragma("unroll")                                                      \
        for (int mb = 0; mb < 2; ++mb)                                         \
            _Pragma("unroll")                                                  \
            for (int r = 0; r < 4; ++r)                                        \
                av[mb * 4 + r] = ap[(size_t)(mb * 16 + r) * NN + (CH) * 64];

    f32x4 agg[2] = {{0,0,0,0},{0,0,0,0}};
    float dpart[8] = {0,0,0,0,0,0,0,0};
    int mb_a = w >> 1, cb0 = (w & 1) * 2;

    // prologue
    STAGE(0)
    LOAD_AV(0)

    for (int ch = 0; ch < 32; ++ch) {
        __syncthreads();   // hxj(ch) DMA complete; P-reads of ch-1 done

        // QK: wave w -> n-tile w (j = w*16+li), both m-tiles, K=256
        f32x4 s0 = {0,0,0,0}, s1 = {0,0,0,0};
#pragma unroll
        for (int ks = 0; ks < 8; ++ks) {
            bf16x8 bfrag = *(const bf16x8*)&hxj[(w * 16 + li) * 256 +
                                                (((ks * 4 + q) ^ (li & 7)) << 3)];
            s0 = __builtin_amdgcn_mfma_f32_16x16x32_bf16(afrag[0][ks], bfrag, s0, 0, 0, 0);
            s1 = __builtin_amdgcn_mfma_f32_16x16x32_bf16(afrag[1][ks], bfrag, s1, 0, 0, 0);
        }

        // PV B-fragments direct from global X2T (L2-resident); ~gate of cover
        bf16x8 xb[2][2];
#pragma unroll
        for (int cbi = 0; cbi < 2; ++cbi)
#pragma unroll
            for (int ks = 0; ks < 2; ++ks)
                xb[cbi][ks] = *(const bf16x8*)&X2T[(size_t)((cb0 + cbi) * 16 + li) * NN
                                                   + jb + ch * 64 + ks * 32 + q * 8];

        // gate + exp, accumulate denom, write P
        {
            int jc = jb + ch * 64 + w * 16 + li;
#pragma unroll
            for (int mb = 0; mb < 2; ++mb) {
                f32x4 sv = mb ? s1 : s0;
#pragma unroll
                for (int r = 0; r < 4; ++r) {
                    int ig = i0 + mb * 16 + q * 4 + r;
                    float s = sv[r];
                    float sig = __builtin_amdgcn_rcpf(1.f + __expf(-s));
                    float wv = (av[mb * 4 + r] > 0.f) ? __expf(sig) : 0.f;
                    if (ig == jc) wv = E_CONST;
                    dpart[mb * 4 + r] += wv;
                    P[(mb * 16 + q * 4 + r) * LDP + w * 16 + li] = (bf16)wv;
                }
            }
        }
        __syncthreads();   // P visible; hxj reads complete

        // issue next chunk's staging + A loads (overlap with PV below)
        if (ch + 1 < 32) {
            STAGE(ch + 1)
            LOAD_AV(ch + 1)
        }

        // PV: agg += P @ X2chunk; wave w -> rows mb_a*16.., col tiles cb0..+1
#pragma unroll
        for (int ks = 0; ks < 2; ++ks) {
            bf16x8 pa = *(const bf16x8*)&P[(mb_a * 16 + li) * LDP + ks * 32 + q * 8];
            agg[0] = __builtin_amdgcn_mfma_f32_16x16x32_bf16(pa, xb[0][ks], agg[0], 0, 0, 0);
            agg[1] = __builtin_amdgcn_mfma_f32_16x16x32_bf16(pa, xb[1][ks], agg[1], 0, 0, 0);
        }
    }
#undef STAGE
#undef LOAD_AV

    // ---- epilogue: cross-wave reduce via LDS (no atomics; js partials) ----
    float* Lf = (float*)hxj;        // 8192 f32 = 32 KB
    float* Pd = (float*)P;          // denominator partials
    float* po = pacc + (size_t)js * NN * DH;
    // each wave's PV quadrant -> Lf[w][col 0..63][row 0..31]
#pragma unroll
    for (int cbi = 0; cbi < 2; ++cbi)
#pragma unroll
        for (int r = 0; r < 4; ++r)
            Lf[w * 2048 + ((cb0 + cbi) * 16 + li) * 32 + mb_a * 16 + q * 4 + r] = agg[cbi][r];
    // denominators: reduce over the 16 li lanes of each quad-group
#pragma unroll
    for (int idx = 0; idx < 8; ++idx) {
        float v = dpart[idx];
        v += __shfl_xor(v, 1, 64);
        v += __shfl_xor(v, 2, 64);
        v += __shfl_xor(v, 4, 64);
        v += __shfl_xor(v, 8, 64);
        if (li == 0)
            Pd[w * 32 + (idx >> 2) * 16 + q * 4 + (idx & 3)] = v;
    }
    __syncthreads();
#pragma unroll
    for (int p = 0; p < 8; ++p) {
        int idx = t + p * 256;      // idx = col*32 + row
        float v = Lf[idx] + Lf[2048 + idx] + Lf[4096 + idx] + Lf[6144 + idx];
        po[(size_t)(i0 + (idx & 31)) * DH + (idx >> 5)] = v;
    }
    if (t < 32) {
        float v = Pd[t] + Pd[32 + t] + Pd[64 + t] + Pd[96 + t];
        pden[(size_t)js * NN + i0 + t] = v;
    }
}

// ---------------------------------------------------------------------------
__global__ __launch_bounds__(256) void k_finalize(const float* __restrict__ pacc,
                                                  const float* __restrict__ pden,
                                                  float* __restrict__ out)
{
    const int S = NN * DH;
    int e = blockIdx.x * 256 + threadIdx.x;
    int i = e >> 6, c = e & 63;
    float num = pacc[e] + pacc[S + e] + pacc[2 * S + e] + pacc[3 * S + e];
    float den = pden[i] + pden[NN + i] + pden[2 * NN + i] + pden[3 * NN + i];
    float v = num / den;
    out[(size_t)i * 128 + 64 + c] = v > 0.f ? v : 0.01f * v;
}

// ---------------------------------------------------------------------------
extern "C" void kernel_launch(void* const* d_in, const int* in_sizes, int n_in,
                              void* d_out, int out_size, void* d_ws, size_t ws_size,
                              hipStream_t stream)
{
    const float* H     = (const float*)d_in[0];
    const float* A     = (const float*)d_in[1];
    const float* gamma = (const float*)d_in[2];
    const float* beta  = (const float*)d_in[3];
    const float* Wt    = (const float*)d_in[4];
    const float* bt    = (const float*)d_in[5];
    const float* W1    = (const float*)d_in[6];
    const float* b1    = (const float*)d_in[7];
    const float* W2    = (const float*)d_in[8];
    const float* b2    = (const float*)d_in[9];
    float* out = (float*)d_out;

    char* ws = (char*)d_ws;
    float* bns  = (float*)(ws + OFF_BN);
    float* pacc = (float*)(ws + OFF_PACC);
    float* pden = (float*)(ws + OFF_PDEN);
    bf16*  Hx   = (bf16*)(ws + OFF_HX);
    bf16*  X2T  = (bf16*)(ws + OFF_X2T);

    hipMemsetAsync(ws + OFF_BN, 0, ZERO_BYTES, stream);
    k_bn_stats<<<256, 256, 0, stream>>>(H, bns);
    k_project<<<512, 256, 0, stream>>>(H, bns, gamma, beta, Wt, bt, W1, b1, W2, b2,
                                       Hx, X2T, out);
    k_fused<<<1024, 256, 0, stream>>>(A, Hx, X2T, pacc, pden);
    k_finalize<<<2048, 256, 0, stream>>>(pacc, pden, out);
}

// Round 6
// 483.773 us; speedup vs baseline: 1.4612x; 1.2434x over previous
//
#include <hip/hip_runtime.h>
#include <hip/hip_bf16.h>

typedef __bf16 bf16;
typedef __bf16 bf16x8 __attribute__((ext_vector_type(8)));
typedef float f32x4 __attribute__((ext_vector_type(4)));

// problem sizes
#define NN 8192
#define DIN 128
#define DTH 256
#define DH 64

// workspace layout (bytes)
#define OFF_PACC 0                         // 8192*64 f32 partial aggregation
#define OFF_PDEN (8192*64*4)               // 8192 f32 partial denominators
#define OFF_BN   (OFF_PDEN + 8192*4)       // 256 f32 bn sums (sum, sumsq)
#define OFF_HX   (OFF_BN + 1024)           // 8192*256 bf16 Hx
#define OFF_X2T  (OFF_HX + 8192*256*2)     // 64*8192 bf16 X2 transposed
#define ZERO_BYTES OFF_HX

// LDS-only barrier: s_barrier WITHOUT the vmcnt(0) drain __syncthreads emits.
// All cross-wave communication in the k_fused main loop is through LDS, so
// lgkmcnt(0) (ds ops retired) + s_barrier gives the same ordering while
// leaving register-destined global loads (A gate stream) in flight.
#define BAR() do { asm volatile("s_waitcnt lgkmcnt(0)" ::: "memory");          \
                   __builtin_amdgcn_s_barrier(); } while (0)

// ---------------------------------------------------------------------------
// BN statistics: per-feature sum and sum-of-squares via per-block partials.
__global__ __launch_bounds__(256) void k_bn_stats(const float* __restrict__ H,
                                                  float* __restrict__ bns) {
    __shared__ float s1[256], s2[256];
    int t = threadIdx.x;
    int f = t & 127, rh = t >> 7;
    int r0 = blockIdx.x * 32 + rh * 16;
    float a = 0.f, b = 0.f;
#pragma unroll
    for (int rr = 0; rr < 16; ++rr) {
        float x = H[(size_t)(r0 + rr) * DIN + f];
        a += x; b += x * x;
    }
    s1[t] = a; s2[t] = b;
    __syncthreads();
    if (t < 128) {
        atomicAdd(&bns[f], s1[t] + s1[t + 128]);
        atomicAdd(&bns[128 + f], s2[t] + s2[t + 128]);
    }
}

// ---------------------------------------------------------------------------
// BN apply + projections: Hx = Hn@Wt+bt (bf16), out1 = leaky(Hn@W1+b1) (fp32,
// written directly to left half of output), X2T[c][row] = Hn@W2+b2 (bf16).
__global__ __launch_bounds__(256) void k_project(
    const float* __restrict__ H, const float* __restrict__ bns,
    const float* __restrict__ gamma, const float* __restrict__ beta,
    const float* __restrict__ Wt, const float* __restrict__ bt,
    const float* __restrict__ W1, const float* __restrict__ b1,
    const float* __restrict__ W2, const float* __restrict__ b2,
    bf16* __restrict__ Hx, bf16* __restrict__ X2T, float* __restrict__ out)
{
    __shared__ float Hn[16 * 128];
    int t = threadIdx.x;
    int r0 = blockIdx.x * 16;
    {   // BN apply: each thread owns feature f = t&127, rows t>>7 + 2p
        int f = t & 127;
        float mean = bns[f] * (1.f / 8192.f);
        float var  = bns[128 + f] * (1.f / 8192.f) - mean * mean;
        float sc = rsqrtf(var + 1e-5f) * gamma[f];
        float sh = beta[f];
        int rb = t >> 7;
#pragma unroll
        for (int p = 0; p < 8; ++p) {
            int row = rb + p * 2;
            float x = H[(size_t)(r0 + row) * DIN + f];
            Hn[row * 128 + f] = (x - mean) * sc + sh;
        }
    }
    __syncthreads();
    {   // Hx = Hn @ Wt + bt : thread -> 4 rows x 4 cols
        int c0 = t & 63, rg = t >> 6;
        float acc[4][4];
#pragma unroll
        for (int i = 0; i < 4; ++i)
#pragma unroll
            for (int j = 0; j < 4; ++j) acc[i][j] = 0.f;
        for (int k = 0; k < 128; ++k) {
            float h[4];
#pragma unroll
            for (int rr = 0; rr < 4; ++rr) h[rr] = Hn[(rg * 4 + rr) * 128 + k];
#pragma unroll
            for (int cc = 0; cc < 4; ++cc) {
                float wv = Wt[k * DTH + c0 + 64 * cc];
#pragma unroll
                for (int rr = 0; rr < 4; ++rr) acc[rr][cc] += h[rr] * wv;
            }
        }
#pragma unroll
        for (int rr = 0; rr < 4; ++rr) {
            int row = r0 + rg * 4 + rr;
#pragma unroll
            for (int cc = 0; cc < 4; ++cc) {
                int c = c0 + 64 * cc;
                Hx[(size_t)row * DTH + c] = (bf16)(acc[rr][cc] + bt[c]);
            }
        }
    }
    {   // out1 (fp32 exact) and X2T (bf16)
        int c = t & 63, rg = t >> 6;
        float a1[4] = {0,0,0,0}, a2[4] = {0,0,0,0};
        for (int k = 0; k < 128; ++k) {
            float w1 = W1[k * DH + c], w2 = W2[k * DH + c];
#pragma unroll
            for (int rr = 0; rr < 4; ++rr) {
                float h = Hn[(rg * 4 + rr) * 128 + k];
                a1[rr] += h * w1; a2[rr] += h * w2;
            }
        }
#pragma unroll
        for (int rr = 0; rr < 4; ++rr) {
            int row = r0 + rg * 4 + rr;
            float v1 = a1[rr] + b1[c];
            out[(size_t)row * 128 + c] = v1 > 0.f ? v1 : 0.01f * v1;
            X2T[(size_t)c * NN + row] = (bf16)(a2[rr] + b2[c]);
        }
    }
}

// ---------------------------------------------------------------------------
// Fused v7 = round-0 kernel with exactly two changes:
//  (1) all main-loop barriers are lgkmcnt-only (BAR): no vmcnt(0) drain, so
//      the A gate stream is never force-completed at a barrier;
//  (2) A gate values ping-pong prefetched 2 chunks deep (avA/avB, compile-
//      time parity), issued after the P-barrier -> ~2 chunks (>3000cy) of
//      cover for the ~900cy HBM latency.
// Everything else (LDS layout, staging, P round-trip, grid, epilogue) is
// identical to the 465us round-0 baseline.
#define LDH 264   // Hx tile LDS row stride (256 + 8 pad, keeps 16B align)
#define LDP 72    // P / X2T LDS row stride (64 + 8 pad)

__global__ __launch_bounds__(256) void k_fused(
    const float* __restrict__ A, const bf16* __restrict__ Hx,
    const bf16* __restrict__ X2T, float* __restrict__ pacc,
    float* __restrict__ pden)
{
    __shared__ __align__(16) bf16 hxi[32 * LDH];   // reused as P after prologue
    __shared__ __align__(16) bf16 hxj[64 * LDH];
    __shared__ __align__(16) bf16 x2t[64 * LDP];
    bf16* P = hxi;

    int t = threadIdx.x;
    int w = t >> 6, l = t & 63;
    int q = l >> 4, li = l & 15;
    int ib = blockIdx.x >> 1, js = blockIdx.x & 1;
    int i0 = ib * 32;
    int jbase = js * 4096;

    // stage Hx_i (32 rows x 256) then preload A-fragments into registers
#pragma unroll
    for (int p = 0; p < 4; ++p) {
        int u = t + p * 256;
        int row = u >> 5, seg = u & 31;
        *(bf16x8*)&hxi[row * LDH + seg * 8] =
            *(const bf16x8*)&Hx[(size_t)(i0 + row) * DTH + seg * 8];
    }
    BAR();
    bf16x8 afrag[2][8];
#pragma unroll
    for (int mb = 0; mb < 2; ++mb)
#pragma unroll
        for (int k = 0; k < 8; ++k)
            afrag[mb][k] = *(const bf16x8*)&hxi[(mb * 16 + li) * LDH + k * 32 + q * 8];
    BAR();   // hxi region now free -> becomes P

    f32x4 agg[2] = {{0,0,0,0},{0,0,0,0}};
    float dpart[8] = {0,0,0,0,0,0,0,0};
    int mb_a = w >> 1, cb0 = (w & 1) * 2;

    // A gate prefetch registers (2 chunks deep, compile-time ping-pong)
    float avA[8], avB[8];
#define LOAD_AV(DST, CH) {                                                     \
        int jc_ = jbase + (CH) * 64 + w * 16 + li;                             \
        _Pragma("unroll")                                                      \
        for (int mb = 0; mb < 2; ++mb)                                         \
            _Pragma("unroll")                                                  \
            for (int r = 0; r < 4; ++r)                                        \
                DST[mb * 4 + r] = A[(size_t)(i0 + mb * 16 + q * 4 + r) * NN + jc_]; \
    }
    LOAD_AV(avA, 0)
    LOAD_AV(avB, 1)

    // one 64-j chunk; AVC = this chunk's gate values (refilled for CH+2)
#define CHUNK(CH, AVC) {                                                       \
        int j0 = jbase + (CH) * 64;                                            \
        /* stage Hx_j chunk (64 rows x 256) */                                 \
        _Pragma("unroll")                                                      \
        for (int p = 0; p < 8; ++p) {                                          \
            int u = t + p * 256;                                               \
            int row = u >> 5, seg = u & 31;                                    \
            *(bf16x8*)&hxj[row * LDH + seg * 8] =                              \
                *(const bf16x8*)&Hx[(size_t)(j0 + row) * DTH + seg * 8];       \
        }                                                                      \
        /* stage X2 chunk transposed: x2t[col][j-local] */                     \
        _Pragma("unroll")                                                      \
        for (int p = 0; p < 2; ++p) {                                          \
            int u = t + p * 256;                                               \
            int c = u >> 3, seg = u & 7;                                       \
            *(bf16x8*)&x2t[c * LDP + seg * 8] =                                \
                *(const bf16x8*)&X2T[(size_t)c * NN + j0 + seg * 8];           \
        }                                                                      \
        BAR();   /* hxj/x2t visible (lgkm-only; A stream stays in flight) */   \
        /* S tiles: wave w covers n-tile w, both m-tiles, K=256 */             \
        f32x4 s0 = {0,0,0,0}, s1 = {0,0,0,0};                                  \
        _Pragma("unroll")                                                      \
        for (int k = 0; k < 8; ++k) {                                          \
            bf16x8 bfrag = *(const bf16x8*)&hxj[(w * 16 + li) * LDH + k * 32 + q * 8]; \
            s0 = __builtin_amdgcn_mfma_f32_16x16x32_bf16(afrag[0][k], bfrag, s0, 0, 0, 0); \
            s1 = __builtin_amdgcn_mfma_f32_16x16x32_bf16(afrag[1][k], bfrag, s1, 0, 0, 0); \
        }                                                                      \
        /* gate + exp, accumulate denom, write P (row-major LDS) */            \
        {                                                                      \
            int jc = j0 + w * 16 + li;                                         \
            _Pragma("unroll")                                                  \
            for (int mb = 0; mb < 2; ++mb) {                                   \
                f32x4 sv = mb ? s1 : s0;                                       \
                _Pragma("unroll")                                              \
                for (int r = 0; r < 4; ++r) {                                  \
                    int ig = i0 + mb * 16 + q * 4 + r;                         \
                    float s = sv[r];                                           \
                    float sig = __builtin_amdgcn_rcpf(1.f + __expf(-s));       \
                    float wv = (AVC[mb * 4 + r] > 0.f) ? __expf(sig) : 0.f;    \
                    if (ig == jc) wv = 2.71828182845904523f;   /* exp(1) */    \
                    dpart[mb * 4 + r] += wv;                                   \
                    P[(mb * 16 + q * 4 + r) * LDP + w * 16 + li] = (bf16)wv;   \
                }                                                              \
            }                                                                  \
        }                                                                      \
        BAR();   /* P visible to all waves */                                  \
        /* prefetch A for chunk CH+2 (never drained by BAR) */                 \
        { int c2 = ((CH) + 2 <= 63) ? (CH) + 2 : 63; LOAD_AV(AVC, c2) }        \
        /* agg += P @ X2chunk */                                               \
        _Pragma("unroll")                                                      \
        for (int ks = 0; ks < 2; ++ks) {                                       \
            bf16x8 pa = *(const bf16x8*)&P[(mb_a * 16 + li) * LDP + ks * 32 + q * 8]; \
            _Pragma("unroll")                                                  \
            for (int cbi = 0; cbi < 2; ++cbi) {                                \
                bf16x8 xb = *(const bf16x8*)&x2t[((cb0 + cbi) * 16 + li) * LDP + ks * 32 + q * 8]; \
                agg[cbi] = __builtin_amdgcn_mfma_f32_16x16x32_bf16(pa, xb, agg[cbi], 0, 0, 0); \
            }                                                                  \
        }                                                                      \
        BAR();   /* all LDS reads done before next staging */                  \
    }

    for (int ch = 0; ch < 64; ch += 2) {
        CHUNK(ch, avA)
        CHUNK(ch + 1, avB)
    }
#undef CHUNK
#undef LOAD_AV

    // write partial aggregation (each output element owned by 1 wave/block)
#pragma unroll
    for (int cbi = 0; cbi < 2; ++cbi)
#pragma unroll
        for (int r = 0; r < 4; ++r)
            atomicAdd(&pacc[(size_t)(i0 + mb_a * 16 + q * 4 + r) * DH + (cb0 + cbi) * 16 + li],
                      agg[cbi][r]);
    // reduce denom partials across the 16 lanes of each quad-group
#pragma unroll
    for (int idx = 0; idx < 8; ++idx) {
        float v = dpart[idx];
        v += __shfl_xor(v, 1, 64);
        v += __shfl_xor(v, 2, 64);
        v += __shfl_xor(v, 4, 64);
        v += __shfl_xor(v, 8, 64);
        if (li == 0)
            atomicAdd(&pden[i0 + (idx >> 2) * 16 + q * 4 + (idx & 3)], v);
    }
}

// ---------------------------------------------------------------------------
__global__ __launch_bounds__(256) void k_finalize(const float* __restrict__ pacc,
                                                  const float* __restrict__ pden,
                                                  float* __restrict__ out)
{
    int e = blockIdx.x * 256 + threadIdx.x;
    int i = e >> 6, c = e & 63;
    float v = pacc[e] / pden[i];
    out[(size_t)i * 128 + 64 + c] = v > 0.f ? v : 0.01f * v;
}

// ---------------------------------------------------------------------------
extern "C" void kernel_launch(void* const* d_in, const int* in_sizes, int n_in,
                              void* d_out, int out_size, void* d_ws, size_t ws_size,
                              hipStream_t stream)
{
    const float* H     = (const float*)d_in[0];
    const float* A     = (const float*)d_in[1];
    const float* gamma = (const float*)d_in[2];
    const float* beta  = (const float*)d_in[3];
    const float* Wt    = (const float*)d_in[4];
    const float* bt    = (const float*)d_in[5];
    const float* W1    = (const float*)d_in[6];
    const float* b1    = (const float*)d_in[7];
    const float* W2    = (const float*)d_in[8];
    const float* b2    = (const float*)d_in[9];
    float* out = (float*)d_out;

    char* ws = (char*)d_ws;
    float* pacc = (float*)(ws + OFF_PACC);
    float* pden = (float*)(ws + OFF_PDEN);
    float* bns  = (float*)(ws + OFF_BN);
    bf16*  Hx   = (bf16*)(ws + OFF_HX);
    bf16*  X2T  = (bf16*)(ws + OFF_X2T);

    hipMemsetAsync(ws, 0, ZERO_BYTES, stream);
    k_bn_stats<<<256, 256, 0, stream>>>(H, bns);
    k_project<<<512, 256, 0, stream>>>(H, bns, gamma, beta, Wt, bt, W1, b1, W2, b2,
                                       Hx, X2T, out);
    k_fused<<<512, 256, 0, stream>>>(A, Hx, X2T, pacc, pden);
    k_finalize<<<2048, 256, 0, stream>>>(pacc, pden, out);
}